// Round 3
// baseline (98.699 us; speedup 1.0000x reference)
//
#include <hip/hip_runtime.h>

// ConvLSTMSNN: the SConv2dLSTM stack can never spike:
//   mem = sigmoid(o)*tanh(syn)  =>  |mem| < 1 strictly,
//   pool2(mem) < 1  =>  spike_ste(pool(mem) - 1.0) == 0  always.
// So spk1/spk2/spk3 == 0 for all t, and the output depends only on the
// FC-path recurrences driven by biases fb1/fb2 (batch-independent):
//   cur     = fb1                          (constant over t and batch)
//   mem4[j] = 0.9*mem4[j] + fb1[j] - (mem4[j] > 1)   [reset from PRIOR mem]
//   spk4[j] = (mem4[j] - 1 > 0)
//   cur2[k] = sum_j spk4[j]*fw2[k][j] + fb2[k]
//   mem5[k] = 0.9*mem5[k] + cur2[k] - (mem5[k] > 1)
//   spk5[k] = (mem5[k] - 1 > 0)
// Output: spk_rec [T,B,2] then mem_rec [T,B,2], each [T,2] row broadcast over B.
//
// R1: single block ~15-20us. R2: 64 redundant blocks + split broadcast, -6us.
// R3: step-3 serial loop was LDS-latency-bound (~120cyc/dependent scalar read
// x100 iters on a 2-thread wave). Fix: cur2 stored transposed, bulk float4
// load into a register array (all ds_read_b128 in flight), fully-unrolled
// register-only recurrence.

#define T_STEPS 100
#define BATCH 64
#define NF 128   // FC1 features
#define NO 2     // FC2 features
#define NBLK 64

__global__ void __launch_bounds__(128)
snn_fc_only_kernel(const float* __restrict__ fb1,   // [128]
                   const float* __restrict__ fw2,   // [2,128]
                   const float* __restrict__ fb2,   // [2]
                   float* __restrict__ out)         // [2*T*B*2] = 25600 floats
{
    __shared__ float  spk4[T_STEPS][NF];     // 51200 B
    __shared__ float  cur2T[NO][T_STEPS];    //   800 B (transposed: row per k)
    __shared__ float2 res_spk[T_STEPS];      //   800 B
    __shared__ float2 res_mem[T_STEPS];      //   800 B

    const int j = threadIdx.x;  // 0..127

    // ---- step 1: per-feature mem4 recurrence (Leaky, reset='subtract')
    {
        float mem4 = 0.0f;
        const float cur = fb1[j];
        #pragma unroll 4
        for (int t = 0; t < T_STEPS; ++t) {
            const float reset = (mem4 > 1.0f) ? 1.0f : 0.0f;  // prior mem, detached
            mem4 = 0.9f * mem4 + cur - reset;
            spk4[t][j] = ((mem4 - 1.0f) > 0.0f) ? 1.0f : 0.0f;
        }
    }
    __syncthreads();

    // ---- step 2: cur2T[k][t] = fb2[k] + sum_j spk4[t][j]*fw2[k][j]
    // 200 (t,k) pairs over 128 threads; float4 LDS reads (spk4 row is
    // 128 contiguous floats, 16B-aligned). fw2 is 1KB -> L1/L2 resident.
    for (int idx = j; idx < T_STEPS * NO; idx += 128) {
        const int t = idx >> 1;
        const int k = idx & 1;
        float s = fb2[k];
        const float4* sp = (const float4*)spk4[t];
        const float4* wr = (const float4*)(fw2 + k * NF);
        #pragma unroll 8
        for (int jj = 0; jj < NF / 4; ++jj) {
            const float4 a = sp[jj];
            const float4 w = wr[jj];
            s += a.x * w.x + a.y * w.y + a.z * w.z + a.w * w.w;
        }
        cur2T[k][t] = s;
    }
    __syncthreads();

    // ---- step 3: mem5 recurrence (2 features). Bulk-load this thread's 100
    // contiguous cur2 values into registers (25x ds_read_b128, all in flight),
    // then a fully-unrolled register-only recurrence.
    if (j < NO) {
        float4 c4[T_STEPS / 4];
        const float4* src = (const float4*)cur2T[j];
        #pragma unroll
        for (int q = 0; q < T_STEPS / 4; ++q) c4[q] = src[q];
        const float* c = (const float*)c4;
        float mem5 = 0.0f;
        #pragma unroll
        for (int t = 0; t < T_STEPS; ++t) {
            const float reset = (mem5 > 1.0f) ? 1.0f : 0.0f;
            mem5 = 0.9f * mem5 + c[t] - reset;
            ((float*)&res_spk[t])[j] = ((mem5 - 1.0f) > 0.0f) ? 1.0f : 0.0f;
            ((float*)&res_mem[t])[j] = mem5;
        }
    }
    __syncthreads();

    // ---- step 4: broadcast over batch, split across blocks, float2 stores.
    // out[t*B*2 + b*2 + k]: per t the pattern (s0,s1) repeats B times.
    float2* __restrict__ o_spk = (float2*)out;
    float2* __restrict__ o_mem = (float2*)(out + T_STEPS * BATCH * NO);
    const int stride = NBLK * 128;
    for (int i = blockIdx.x * 128 + j; i < T_STEPS * BATCH; i += stride) {
        const int t = i >> 6;  // i / BATCH
        o_spk[i] = res_spk[t];
        o_mem[i] = res_mem[t];
    }
}

extern "C" void kernel_launch(void* const* d_in, const int* in_sizes, int n_in,
                              void* d_out, int out_size, void* d_ws, size_t ws_size,
                              hipStream_t stream) {
    // setup_inputs order: x, w1, b1, w2, b2, w3, b3, fw1, fb1, fw2, fb2
    const float* fb1 = (const float*)d_in[8];
    const float* fw2 = (const float*)d_in[9];
    const float* fb2 = (const float*)d_in[10];
    float* out = (float*)d_out;

    snn_fc_only_kernel<<<NBLK, 128, 0, stream>>>(fb1, fw2, fb2, out);
}